// Round 5
// baseline (339.008 us; speedup 1.0000x reference)
//
#include <hip/hip_runtime.h>
#include <math.h>

#define C_DIM 512
#define K_DIM 64
#define N_PIX 784
#define B_DIM 128
#define M_ROWS (B_DIM * N_PIX)   // 100352
#define MT 128                    // rows per block tile
#define KC 32                     // K chunk (one 16x16x32 K-step)
#define XS 40                     // LDS row stride in ushorts (80 B = odd multiple of 16B)
#define NCH (C_DIM / KC)          // 16 chunks

// exp(20*d - 20) = exp2(KA*d + KB)
#define KA 28.853900817779268f
#define KB (-28.853900817779268f)

typedef __attribute__((ext_vector_type(8))) short short8;            // MFMA A/B frag (8 bf16)
typedef __attribute__((ext_vector_type(4))) float f32x4;             // MFMA C/D frag
typedef __attribute__((ext_vector_type(8))) unsigned short ushort8;  // 16B

static __device__ __forceinline__ unsigned short f2bf(float f) {
    unsigned u = __builtin_bit_cast(unsigned, f);
    u += 0x7fff + ((u >> 16) & 1);  // RNE
    return (unsigned short)(u >> 16);
}
static __device__ __forceinline__ float bf2f(unsigned short h) {
    unsigned u = ((unsigned)h) << 16;
    return __builtin_bit_cast(float, u);
}
static __device__ __forceinline__ unsigned pk_bf16(float a, float b) {
    return (unsigned)f2bf(a) | ((unsigned)f2bf(b) << 16);
}

// ---------------- Kernel A: normalize anchors -> bf16 hi/lo in MFMA-frag order --------------
// Packed layout (ushort8 granularity): frag for (chunk ch, col-tile ct, lane l) at
// index ((ch*4 + ct)*64 + l), holding B[r=ct*16+(l&15)][k=ch*32+(l>>4)*8 .. +7].
// Thread l of anchor-row k handles cols 8l..8l+7 -> exactly one frag slot.
__global__ __launch_bounds__(64) void anchors_norm_kernel(const float* __restrict__ a,
                                                          ushort8* __restrict__ an_h,
                                                          ushort8* __restrict__ an_l) {
    const int k = blockIdx.x;
    const int l = threadIdx.x;  // 0..63
    const float4* ap = (const float4*)(a + (size_t)k * C_DIM);
    float4 v0 = ap[2 * l];       // cols 8l..8l+3
    float4 v1 = ap[2 * l + 1];   // cols 8l+4..8l+7
    float ss = v0.x * v0.x + v0.y * v0.y + v0.z * v0.z + v0.w * v0.w +
               v1.x * v1.x + v1.y * v1.y + v1.z * v1.z + v1.w * v1.w;
#pragma unroll
    for (int m = 1; m < 64; m <<= 1) ss += __shfl_xor(ss, m);
    const float rn = 1.0f / (sqrtf(ss) + 1e-12f);
    const float vv[8] = {v0.x * rn, v0.y * rn, v0.z * rn, v0.w * rn,
                         v1.x * rn, v1.y * rn, v1.z * rn, v1.w * rn};
    ushort8 H, L;
#pragma unroll
    for (int i = 0; i < 8; ++i) {
        const unsigned short h = f2bf(vv[i]);
        H[i] = h;
        L[i] = f2bf(vv[i] - bf2f(h));
    }
    // ch = l>>2 ; ct = k>>4 ; lane' = (k&15) | ((l&3)<<4)
    const int idx = (((l >> 2) * 4 + (k >> 4)) * 64) + ((k & 15) | ((l & 3) << 4));
    an_h[idx] = H;
    an_l[idx] = L;
}

// ---------------- Kernel B: cosine GEMM via MFMA + T ----------------
// 784 blocks x 256 threads (4 waves). Block tile 128 rows x 64 anchors.
// x: single bf16 (RNE) staged in LDS; anchors: hi/lo read directly from global (L2-hot,
// coalesced 16B/lane in frag order). d ~= xh.(ah+al); dropped xl.a term ~2e-4 max.
// C/D layout: col(anchor)=lane&15, row=(lane>>4)*4+reg (verified R3).
__global__ __launch_bounds__(256) void cost_t_kernel(const float* __restrict__ x,
                                                     const ushort8* __restrict__ an_h,
                                                     const ushort8* __restrict__ an_l,
                                                     float* __restrict__ Tg) {
    __shared__ __align__(16) unsigned short xs[MT * XS];  // 10240 B
    __shared__ float nrm[MT];

    const int tid = threadIdx.x;
    const int m0 = blockIdx.x * MT;
    const int w = tid >> 6;   // wave 0..3
    const int l = tid & 63;   // lane

    // x staging: thread -> row xr (0..127), half hf (cols hf*16..+15 of the chunk)
    const int xr = tid >> 1;
    const int hf = tid & 1;
    const float* xrow = x + (size_t)(m0 + xr) * C_DIM + hf * 16;

    f32x4 acc[2][4];
#pragma unroll
    for (int rt = 0; rt < 2; ++rt)
#pragma unroll
        for (int ct = 0; ct < 4; ++ct) acc[rt][ct] = (f32x4){0.f, 0.f, 0.f, 0.f};
    float ss = 0.f;

    float4 px[4];
#pragma unroll
    for (int i = 0; i < 4; ++i) px[i] = *(const float4*)(xrow + i * 4);

    const int fr = l & 15;
    const int koB = (l >> 4) * 8;  // ushort offset of A-frag k-slice

    for (int ch = 0; ch < NCH; ++ch) {
        __syncthreads();  // previous chunk's LDS reads complete
        // convert 16 floats -> 8 packed bf16 pairs, stage as 2x b128; accumulate sumsq
        uint4 P0, P1;
        P0.x = pk_bf16(px[0].x, px[0].y); P0.y = pk_bf16(px[0].z, px[0].w);
        P0.z = pk_bf16(px[1].x, px[1].y); P0.w = pk_bf16(px[1].z, px[1].w);
        P1.x = pk_bf16(px[2].x, px[2].y); P1.y = pk_bf16(px[2].z, px[2].w);
        P1.z = pk_bf16(px[3].x, px[3].y); P1.w = pk_bf16(px[3].z, px[3].w);
#pragma unroll
        for (int i = 0; i < 4; ++i)
            ss += px[i].x * px[i].x + px[i].y * px[i].y + px[i].z * px[i].z + px[i].w * px[i].w;
        *(uint4*)&xs[xr * XS + hf * 16] = P0;
        *(uint4*)&xs[xr * XS + hf * 16 + 8] = P1;
        __syncthreads();

        // prefetch next chunk's x (overlaps MFMA below)
        if (ch + 1 < NCH) {
            const int c0 = (ch + 1) * KC;
#pragma unroll
            for (int i = 0; i < 4; ++i) px[i] = *(const float4*)(xrow + c0 + i * 4);
        }

        // B frags straight from global (L2-hot, coalesced)
        const int bbase = ch * 4 * 64 + l;
        short8 bh[4], bl[4];
#pragma unroll
        for (int ct = 0; ct < 4; ++ct) {
            bh[ct] = __builtin_bit_cast(short8, an_h[bbase + ct * 64]);
            bl[ct] = __builtin_bit_cast(short8, an_l[bbase + ct * 64]);
        }
        // A frags from LDS
        short8 ax[2];
#pragma unroll
        for (int rt = 0; rt < 2; ++rt) {
            const int row = w * 32 + rt * 16 + fr;
            ax[rt] = *(const short8*)&xs[row * XS + koB];
        }
#pragma unroll
        for (int ct = 0; ct < 4; ++ct)
#pragma unroll
            for (int rt = 0; rt < 2; ++rt) {
                acc[rt][ct] = __builtin_amdgcn_mfma_f32_16x16x32_bf16(ax[rt], bh[ct], acc[rt][ct], 0, 0, 0);
                acc[rt][ct] = __builtin_amdgcn_mfma_f32_16x16x32_bf16(ax[rt], bl[ct], acc[rt][ct], 0, 0, 0);
            }
    }

    // row inverse norms: lane pair (bit0 of tid) shares a row
    ss += __shfl_xor(ss, 1);
    if ((tid & 1) == 0) nrm[xr] = 1.0f / (sqrtf(ss) + 1e-12f);
    __syncthreads();

    // epilogue: T[m] = sum_k exp(20*cos - 20)
#pragma unroll
    for (int rt = 0; rt < 2; ++rt) {
#pragma unroll
        for (int i = 0; i < 4; ++i) {
            const int m = w * 32 + rt * 16 + ((l >> 4) << 2) + i;
            const float rn = nrm[m];
            float t = exp2f(KA * (acc[rt][0][i] * rn) + KB) +
                      exp2f(KA * (acc[rt][1][i] * rn) + KB) +
                      exp2f(KA * (acc[rt][2][i] * rn) + KB) +
                      exp2f(KA * (acc[rt][3][i] * rn) + KB);
            t += __shfl_xor(t, 1); t += __shfl_xor(t, 2);
            t += __shfl_xor(t, 4); t += __shfl_xor(t, 8);
            if ((l & 15) == 0) Tg[m0 + m] = t;
        }
    }
}

// ---------------- Kernel C: Sinkhorn scalar recurrence, in-place coef ----------------
// w_{t+1} = w_t * (mu*N) / sum_n (w T)/(1+w T);  coef = (2/N) * wT/(1+wT)
__global__ __launch_bounds__(256) void sinkhorn_kernel(float* __restrict__ Tc) {
    const int b = blockIdx.x;
    const int tid = threadIdx.x;
    __shared__ float wsum[4];
    __shared__ float wsh;
    float r[4];
#pragma unroll
    for (int q = 0; q < 4; ++q) {
        const int n = tid + q * 256;
        r[q] = (n < N_PIX) ? Tc[b * N_PIX + n] : 0.f;
    }
    float w = 1.0f;
    for (int it = 0; it < 10; ++it) {
        float p = 0.f;
#pragma unroll
        for (int q = 0; q < 4; ++q) {
            const float wr = w * r[q];
            p += wr / (1.0f + wr);
        }
#pragma unroll
        for (int m = 1; m < 64; m <<= 1) p += __shfl_xor(p, m);
        if ((tid & 63) == 0) wsum[tid >> 6] = p;
        __syncthreads();
        if (tid == 0) {
            const float s = wsum[0] + wsum[1] + wsum[2] + wsum[3];
            wsh = w * 392.0f / s;  // mu*N = 0.5*784
        }
        __syncthreads();
        w = wsh;
    }
    const float scale = 2.0f / 784.0f;
#pragma unroll
    for (int q = 0; q < 4; ++q) {
        const int n = tid + q * 256;
        if (n < N_PIX) {
            const float wr = w * r[q];
            Tc[b * N_PIX + n] = scale * wr / (1.0f + wr);
        }
    }
}

// ---------------- Kernel D: weighted pooling, float4, no atomics ----------------
// 512 blocks = (batch, quarter of 196 rows); waves 0-1 even rows, 2-3 odd rows.
__global__ __launch_bounds__(256) void pool_partial(const float* __restrict__ x,
                                                    const float* __restrict__ coef,
                                                    float* __restrict__ part) {
    const int bid = blockIdx.x;
    const int b = bid >> 2;
    const int q = bid & 3;
    const int half = threadIdx.x >> 7;       // 0/1 (wave-uniform)
    const int c4 = (threadIdx.x & 127) * 4;  // channel float4
    const float* xb = x + (size_t)b * N_PIX * C_DIM + (size_t)(q * 196) * C_DIM + c4;
    const float* cf = coef + b * N_PIX + q * 196;
    float4 acc = {0.f, 0.f, 0.f, 0.f};
#pragma unroll 7
    for (int i = 0; i < 98; ++i) {
        const int n = 2 * i + half;
        const float a = cf[n];  // wave-uniform -> scalar load
        const float4 xv = *(const float4*)(xb + (size_t)n * C_DIM);
        acc.x += a * xv.x; acc.y += a * xv.y; acc.z += a * xv.z; acc.w += a * xv.w;
    }
    *(float4*)(part + (size_t)(bid * 2 + half) * C_DIM + c4) = acc;
}

__global__ __launch_bounds__(256) void pool_reduce(const float* __restrict__ part,
                                                   float* __restrict__ out) {
    const int i = blockIdx.x * 256 + threadIdx.x;  // over b*512 + c
    const int b = i >> 9;
    const int c = i & 511;
    const float* p = part + (size_t)b * 8 * C_DIM + c;
    float s = 0.f;
#pragma unroll
    for (int j = 0; j < 8; ++j) s += p[j * C_DIM];
    out[i] = s;
}

extern "C" void kernel_launch(void* const* d_in, const int* in_sizes, int n_in,
                              void* d_out, int out_size, void* d_ws, size_t ws_size,
                              hipStream_t stream) {
    const float* x = (const float*)d_in[0];       // (128,28,28,512) fp32
    const float* anchors = (const float*)d_in[1]; // (64,512) fp32
    float* out = (float*)d_out;                   // (128,512) fp32

    ushort8* an_h = (ushort8*)d_ws;                       // 64*512 ushort = 4096 frags
    ushort8* an_l = an_h + 4096;                          // 64*512 ushort
    float* Tc = (float*)(an_l + 4096);                    // 128*784 fp32
    float* part = Tc + (size_t)B_DIM * N_PIX;             // 1024*512 fp32

    anchors_norm_kernel<<<K_DIM, 64, 0, stream>>>(anchors, an_h, an_l);
    cost_t_kernel<<<M_ROWS / MT, 256, 0, stream>>>(x, an_h, an_l, Tc);
    sinkhorn_kernel<<<B_DIM, 256, 0, stream>>>(Tc);
    pool_partial<<<B_DIM * 4, 256, 0, stream>>>(x, Tc, part);
    pool_reduce<<<B_DIM * C_DIM / 256, 256, 0, stream>>>(part, out);
}

// Round 6
// 329.685 us; speedup vs baseline: 1.0283x; 1.0283x over previous
//
#include <hip/hip_runtime.h>
#include <math.h>

#define C_DIM 512
#define K_DIM 64
#define N_PIX 784
#define B_DIM 128
#define M_ROWS (B_DIM * N_PIX)   // 100352
#define MT 128                    // rows per block tile
#define NCH 16                    // 512 / 32 chunks

// exp(20*d - 20) = exp2(KA*d + KB)
#define KA 28.853900817779268f
#define KB (-28.853900817779268f)

typedef __attribute__((ext_vector_type(8))) short short8;            // MFMA A/B frag (8 bf16)
typedef __attribute__((ext_vector_type(4))) float f32x4;             // MFMA C/D frag
typedef __attribute__((ext_vector_type(8))) unsigned short ushort8;  // 16B

static __device__ __forceinline__ unsigned short f2bf(float f) {
    unsigned u = __builtin_bit_cast(unsigned, f);
    u += 0x7fff + ((u >> 16) & 1);  // RNE
    return (unsigned short)(u >> 16);
}
static __device__ __forceinline__ float bf2f(unsigned short h) {
    unsigned u = ((unsigned)h) << 16;
    return __builtin_bit_cast(float, u);
}
static __device__ __forceinline__ unsigned pk_bf16(float a, float b) {
    return (unsigned)f2bf(a) | ((unsigned)f2bf(b) << 16);
}

// ---------------- Kernel A: normalize anchors -> bf16 hi/lo in MFMA-frag order --------------
// Frag for (chunk ch, col-tile ct, lane L) at index ((ch*4+ct)*64 + L), holding
// B[r = ct*16 + (L&15)][k = ch*32 + (L>>4)*8 .. +7]. (verified R5)
__global__ __launch_bounds__(64) void anchors_norm_kernel(const float* __restrict__ a,
                                                          ushort8* __restrict__ an_h,
                                                          ushort8* __restrict__ an_l) {
    const int k = blockIdx.x;
    const int l = threadIdx.x;  // 0..63
    const float4* ap = (const float4*)(a + (size_t)k * C_DIM);
    float4 v0 = ap[2 * l];       // cols 8l..8l+3
    float4 v1 = ap[2 * l + 1];   // cols 8l+4..8l+7
    float ss = v0.x * v0.x + v0.y * v0.y + v0.z * v0.z + v0.w * v0.w +
               v1.x * v1.x + v1.y * v1.y + v1.z * v1.z + v1.w * v1.w;
#pragma unroll
    for (int m = 1; m < 64; m <<= 1) ss += __shfl_xor(ss, m);
    const float rn = 1.0f / (sqrtf(ss) + 1e-12f);
    const float vv[8] = {v0.x * rn, v0.y * rn, v0.z * rn, v0.w * rn,
                         v1.x * rn, v1.y * rn, v1.z * rn, v1.w * rn};
    ushort8 H, L;
#pragma unroll
    for (int i = 0; i < 8; ++i) {
        const unsigned short h = f2bf(vv[i]);
        H[i] = h;
        L[i] = f2bf(vv[i] - bf2f(h));
    }
    const int idx = (((l >> 2) * 4 + (k >> 4)) * 64) + ((k & 15) | ((l & 3) << 4));
    an_h[idx] = H;
    an_l[idx] = L;
}

// ---------------- Kernel B: cosine GEMM via MFMA + T — barrier-free ----------------
// 784 blocks x 256 threads (4 waves). Block tile 128 rows x 64 anchors; wave w owns
// rows w*32..+31. A-frags straight from global f32 (lane reads rows w*32+fr and +16,
// k-slice (l>>4)*8: 4 lanes sharing fr cover one contiguous 128B span per row).
// B hi/lo frags from global (L2-hot, frag order). No x LDS, no in-loop barriers.
__global__ __launch_bounds__(256) void cost_t_kernel(const float* __restrict__ x,
                                                     const ushort8* __restrict__ an_h,
                                                     const ushort8* __restrict__ an_l,
                                                     float* __restrict__ Tg) {
    __shared__ float nrm[MT];

    const int tid = threadIdx.x;
    const int m0 = blockIdx.x * MT;
    const int w = tid >> 6;   // wave 0..3
    const int l = tid & 63;   // lane
    const int fr = l & 15;
    const int ko = (l >> 4) * 8;  // k offset within chunk (floats)

    const float* xr0 = x + (size_t)(m0 + w * 32 + fr) * C_DIM + ko;
    const float* xr1 = xr0 + 16 * C_DIM;

    f32x4 acc[2][4];
#pragma unroll
    for (int rt = 0; rt < 2; ++rt)
#pragma unroll
        for (int ct = 0; ct < 4; ++ct) acc[rt][ct] = (f32x4){0.f, 0.f, 0.f, 0.f};
    float ss0 = 0.f, ss1 = 0.f;

    // prefetch chunk 0
    float4 p0a = *(const float4*)(xr0);
    float4 p0b = *(const float4*)(xr0 + 4);
    float4 p1a = *(const float4*)(xr1);
    float4 p1b = *(const float4*)(xr1 + 4);
    const ushort8* bhp = an_h + l;
    const ushort8* blp = an_l + l;
    ushort8 bh[4], bl[4];
#pragma unroll
    for (int ct = 0; ct < 4; ++ct) { bh[ct] = bhp[ct * 64]; bl[ct] = blp[ct * 64]; }

#pragma unroll 1
    for (int ch = 0; ch < NCH; ++ch) {
        // convert current x to A-frags + sumsq
        ushort8 A0, A1;
        *((unsigned*)&A0 + 0) = pk_bf16(p0a.x, p0a.y);
        *((unsigned*)&A0 + 1) = pk_bf16(p0a.z, p0a.w);
        *((unsigned*)&A0 + 2) = pk_bf16(p0b.x, p0b.y);
        *((unsigned*)&A0 + 3) = pk_bf16(p0b.z, p0b.w);
        *((unsigned*)&A1 + 0) = pk_bf16(p1a.x, p1a.y);
        *((unsigned*)&A1 + 1) = pk_bf16(p1a.z, p1a.w);
        *((unsigned*)&A1 + 2) = pk_bf16(p1b.x, p1b.y);
        *((unsigned*)&A1 + 3) = pk_bf16(p1b.z, p1b.w);
        ss0 += p0a.x * p0a.x + p0a.y * p0a.y + p0a.z * p0a.z + p0a.w * p0a.w +
               p0b.x * p0b.x + p0b.y * p0b.y + p0b.z * p0b.z + p0b.w * p0b.w;
        ss1 += p1a.x * p1a.x + p1a.y * p1a.y + p1a.z * p1a.z + p1a.w * p1a.w +
               p1b.x * p1b.x + p1b.y * p1b.y + p1b.z * p1b.z + p1b.w * p1b.w;
        const short8 a0 = __builtin_bit_cast(short8, A0);
        const short8 a1 = __builtin_bit_cast(short8, A1);
        ushort8 cbh[4], cbl[4];
#pragma unroll
        for (int ct = 0; ct < 4; ++ct) { cbh[ct] = bh[ct]; cbl[ct] = bl[ct]; }

        // prefetch next chunk (overlaps MFMAs)
        if (ch + 1 < NCH) {
            const int c0 = (ch + 1) * 32;
            p0a = *(const float4*)(xr0 + c0);
            p0b = *(const float4*)(xr0 + c0 + 4);
            p1a = *(const float4*)(xr1 + c0);
            p1b = *(const float4*)(xr1 + c0 + 4);
            const int bb = (ch + 1) * 4 * 64;
#pragma unroll
            for (int ct = 0; ct < 4; ++ct) {
                bh[ct] = bhp[bb + ct * 64];
                bl[ct] = blp[bb + ct * 64];
            }
        }

#pragma unroll
        for (int ct = 0; ct < 4; ++ct) {
            const short8 h = __builtin_bit_cast(short8, cbh[ct]);
            const short8 lo = __builtin_bit_cast(short8, cbl[ct]);
            acc[0][ct] = __builtin_amdgcn_mfma_f32_16x16x32_bf16(a0, h, acc[0][ct], 0, 0, 0);
            acc[0][ct] = __builtin_amdgcn_mfma_f32_16x16x32_bf16(a0, lo, acc[0][ct], 0, 0, 0);
            acc[1][ct] = __builtin_amdgcn_mfma_f32_16x16x32_bf16(a1, h, acc[1][ct], 0, 0, 0);
            acc[1][ct] = __builtin_amdgcn_mfma_f32_16x16x32_bf16(a1, lo, acc[1][ct], 0, 0, 0);
        }
    }

    // full-row sumsq: lanes {l, l+16, l+32, l+48} hold complementary k-slices
    ss0 += __shfl_xor(ss0, 16); ss0 += __shfl_xor(ss0, 32);
    ss1 += __shfl_xor(ss1, 16); ss1 += __shfl_xor(ss1, 32);
    if (l < 16) {
        nrm[w * 32 + fr] = 1.0f / (sqrtf(ss0) + 1e-12f);
        nrm[w * 32 + 16 + fr] = 1.0f / (sqrtf(ss1) + 1e-12f);
    }
    __syncthreads();

    // epilogue: C/D layout col=l&15, row=(l>>4)*4+i ; T[m] = sum_k exp(20*cos - 20)
#pragma unroll
    for (int rt = 0; rt < 2; ++rt) {
#pragma unroll
        for (int i = 0; i < 4; ++i) {
            const int m = w * 32 + rt * 16 + ((l >> 4) << 2) + i;
            const float rn = nrm[m];
            float t = exp2f(KA * (acc[rt][0][i] * rn) + KB) +
                      exp2f(KA * (acc[rt][1][i] * rn) + KB) +
                      exp2f(KA * (acc[rt][2][i] * rn) + KB) +
                      exp2f(KA * (acc[rt][3][i] * rn) + KB);
            t += __shfl_xor(t, 1); t += __shfl_xor(t, 2);
            t += __shfl_xor(t, 4); t += __shfl_xor(t, 8);
            if ((l & 15) == 0) Tg[m0 + m] = t;
        }
    }
}

// ---------------- Kernel C: fused sinkhorn + weighted pooling ----------------
// 512 blocks = (batch, quarter). Each block redundantly runs the scalar sinkhorn
// recurrence for its batch (reads T[b,:], 10 iters), builds coef for its 196 rows
// in LDS, then pools. w_{t+1} = w * (mu*N) / sum_n wT/(1+wT); coef = (2/N)*wT/(1+wT).
__global__ __launch_bounds__(256) void pool_partial(const float* __restrict__ x,
                                                    const float* __restrict__ Tg,
                                                    float* __restrict__ part) {
    const int bid = blockIdx.x;
    const int b = bid >> 2;
    const int q = bid & 3;
    const int tid = threadIdx.x;
    __shared__ float wsum[4];
    __shared__ float wsh;
    __shared__ float cf[196];

    float r[4];
#pragma unroll
    for (int qq = 0; qq < 4; ++qq) {
        const int n = tid + qq * 256;
        r[qq] = (n < N_PIX) ? Tg[b * N_PIX + n] : 0.f;
    }
    float w = 1.0f;
    for (int it = 0; it < 10; ++it) {
        float p = 0.f;
#pragma unroll
        for (int qq = 0; qq < 4; ++qq) {
            const float wr = w * r[qq];
            p += wr / (1.0f + wr);
        }
#pragma unroll
        for (int m = 1; m < 64; m <<= 1) p += __shfl_xor(p, m);
        if ((tid & 63) == 0) wsum[tid >> 6] = p;
        __syncthreads();
        if (tid == 0) {
            const float s = wsum[0] + wsum[1] + wsum[2] + wsum[3];
            wsh = w * 392.0f / s;  // mu*N = 0.5*784
        }
        __syncthreads();
        w = wsh;
    }
    if (tid < 196) {
        const float wr = w * Tg[b * N_PIX + q * 196 + tid];
        cf[tid] = (2.0f / 784.0f) * wr / (1.0f + wr);
    }
    __syncthreads();

    const int half = tid >> 7;       // 0/1 (wave-uniform)
    const int c4 = (tid & 127) * 4;  // channel float4
    const float* xb = x + ((size_t)b * N_PIX + q * 196) * C_DIM + c4;
    float4 acc = {0.f, 0.f, 0.f, 0.f};
#pragma unroll 7
    for (int i = 0; i < 98; ++i) {
        const int n = 2 * i + half;
        const float a = cf[n];  // wave-uniform LDS broadcast
        const float4 xv = *(const float4*)(xb + (size_t)n * C_DIM);
        acc.x += a * xv.x; acc.y += a * xv.y; acc.z += a * xv.z; acc.w += a * xv.w;
    }
    *(float4*)(part + (size_t)(bid * 2 + half) * C_DIM + c4) = acc;
}

__global__ __launch_bounds__(256) void pool_reduce(const float* __restrict__ part,
                                                   float* __restrict__ out) {
    const int i = blockIdx.x * 256 + threadIdx.x;  // over b*512 + c
    const int b = i >> 9;
    const int c = i & 511;
    const float* p = part + (size_t)b * 8 * C_DIM + c;
    float s = 0.f;
#pragma unroll
    for (int j = 0; j < 8; ++j) s += p[j * C_DIM];
    out[i] = s;
}

extern "C" void kernel_launch(void* const* d_in, const int* in_sizes, int n_in,
                              void* d_out, int out_size, void* d_ws, size_t ws_size,
                              hipStream_t stream) {
    const float* x = (const float*)d_in[0];       // (128,28,28,512) fp32
    const float* anchors = (const float*)d_in[1]; // (64,512) fp32
    float* out = (float*)d_out;                   // (128,512) fp32

    ushort8* an_h = (ushort8*)d_ws;                       // 4096 frags
    ushort8* an_l = an_h + 4096;
    float* Tg = (float*)(an_l + 4096);                    // 128*784 fp32
    float* part = Tg + (size_t)B_DIM * N_PIX;             // 1024*512 fp32

    anchors_norm_kernel<<<K_DIM, 64, 0, stream>>>(anchors, an_h, an_l);
    cost_t_kernel<<<M_ROWS / MT, 256, 0, stream>>>(x, an_h, an_l, Tg);
    pool_partial<<<B_DIM * 4, 256, 0, stream>>>(x, Tg, part);
    pool_reduce<<<B_DIM * C_DIM / 256, 256, 0, stream>>>(part, out);
}